// Round 7
// baseline (360.409 us; speedup 1.0000x reference)
//
#include <hip/hip_runtime.h>
#include <cstdint>
#include <cstddef>

// Model dims
#define Hn 100
#define Tn 25
#define Bn 512
#define FCn 128
#define ROWS 16              // batch rows per block (= MFMA M)
#define NBLK (Bn / ROWS)     // 32 blocks (structural: h is block-local)
#define NTHR 1024            // 16 waves -> 4 waves/SIMD on the one active CU
#define PITCH 232            // fp16 row pitch: 16B-aligned rows
#define KPAD 224             // K padded to 7*32

typedef _Float16 v8h __attribute__((ext_vector_type(8)));
typedef float    v4f __attribute__((ext_vector_type(4)));
union U4H8 { uint4 u; v8h h; };

__device__ __forceinline__ float sigm(float x) {
    return __fdividef(1.0f, 1.0f + __expf(-x));
}
__device__ __forceinline__ float tanh_fast(float x) {
    float e = __expf(2.0f * x);
    return __fdividef(e - 1.0f, e + 1.0f);
}

// ---------------------------------------------------------------------------
// Prep: repack k1,k2 (fp32 [200][400], orig col c = g*100+u) into MFMA
// B-fragments, with PERMUTED columns col' = 4u+g (so a unit's 4 gates are
// quad-adjacent in one tile). WB[((l*25+t)*7+kk)*64 + lane], lane = q*16+n:
// uint4 = 8 fp16 = K[kk*32+q*8 .. +8][col'=16t+n], zeros for k>=200.
// ---------------------------------------------------------------------------
__global__ void prep_weights(const float* __restrict__ k1,
                             const float* __restrict__ k2,
                             uint4* __restrict__ WB) {
    int t = blockIdx.x * 256 + threadIdx.x;
    if (t >= 2 * 25 * 7 * 64) return;
    int lane = t & 63;
    int rest = t >> 6;               // (l*25 + tile)*7 + kk
    int kk   = rest % 7;
    int tile = (rest / 7) % 25;
    int l    = rest / (7 * 25);
    int q = lane >> 4, n = lane & 15;
    int colp = tile * 16 + n;        // permuted col'
    int u = colp >> 2, g = colp & 3;
    int c = g * 100 + u;             // original kernel column
    int k0 = kk * 32 + q * 8;
    const float* K = l ? k2 : k1;
    union { unsigned u32; _Float16 h[2]; } d[4];
    #pragma unroll
    for (int j = 0; j < 4; j++) {
        int ka = k0 + 2 * j, kb = ka + 1;
        d[j].h[0] = (_Float16)((ka < 200) ? K[ka * 400 + c] : 0.0f);
        d[j].h[1] = (_Float16)((kb < 200) ? K[kb * 400 + c] : 0.0f);
    }
    uint4 v; v.x = d[0].u32; v.y = d[1].u32; v.z = d[2].u32; v.w = d[3].u32;
    WB[t] = v;
}

// Quad 4x4 transpose + LSTM cell update. acc reg r = z[row 4q+r][col' 16t+n];
// lane ends up owning (row 4q+g, unit 4t+v). Verified bit-exact in r5/r6.
__device__ __forceinline__ float cell_update(v4f acc, int g, float& cst) {
    float a0 = acc[0], a1 = acc[1], a2 = acc[2], a3 = acc[3];
    bool gb0 = (g & 1) != 0, gb1 = (g & 2) != 0;
    float selA  = gb0 ? a1 : a0;     // a[g&1]
    float selB  = gb0 ? a3 : a2;     // a[2|(g&1)]
    float selA1 = gb0 ? a0 : a1;
    float selB1 = gb0 ? a2 : a3;
    float s0 = gb1 ? selB  : selA;   // a[g]
    float s1 = gb1 ? selB1 : selA1;  // a[g^1]
    float s2 = gb1 ? selA  : selB;   // a[g^2]
    float s3 = gb1 ? selA1 : selB1;  // a[g^3]
    float w0 = s0;
    float w1 = __shfl_xor(s1, 1);
    float w2 = __shfl_xor(s2, 2);
    float w3 = __shfl_xor(s3, 3);
    float p01 = gb0 ? w1 : w0;
    float p10 = gb0 ? w0 : w1;
    float p23 = gb0 ? w3 : w2;
    float p32 = gb0 ? w2 : w3;
    float zi = gb1 ? p23 : p01;      // w_g
    float zj = gb1 ? p32 : p10;      // w_{g^1}
    float zf = gb1 ? p01 : p23;      // w_{g^2}
    float zo = gb1 ? p10 : p32;      // w_{g^3}
    float cn = cst * sigm(zf + 1.0f) + sigm(zi) * tanh_fast(zj);  // fb=1
    cst = cn;
    return tanh_fast(cn) * sigm(zo);
}

// ---------------------------------------------------------------------------
// One layer phase for one wave handling tiles {t0} or {t0, t0+16}.
// Sequenced to cap live B at ~2 tiles: B0+A loads -> mfma0 -> issue B1 ->
// update0 (overlaps B1 L2 latency) -> mfma1 -> update1.
// ---------------------------------------------------------------------------
template<bool TWO>
__device__ __forceinline__ void layer_phase(
    const uint4* __restrict__ WBl, int t0,
    const _Float16* __restrict__ xsrc,
    _Float16* __restrict__ dstA, int offA,
    _Float16* __restrict__ dstB, int offB,     // nullptr -> single dest
    const float* __restrict__ bl,
    float* __restrict__ cst,
    int lane)
{
    const int q = lane >> 4, n = lane & 15;
    const int g = n & 3, v = n >> 2;

    U4H8 b0[7];
    #pragma unroll
    for (int kk = 0; kk < 7; kk++)
        b0[kk].u = WBl[(t0 * 7 + kk) * 64 + lane];
    U4H8 af[7];
    #pragma unroll
    for (int kk = 0; kk < 7; kk++)
        af[kk].u = *(const uint4*)(xsrc + n * PITCH + kk * 32 + q * 8);

    v4f acc0 = { bl[0], bl[0], bl[0], bl[0] };
    #pragma unroll
    for (int kk = 0; kk < 7; kk++)
        acc0 = __builtin_amdgcn_mfma_f32_16x16x32_f16(af[kk].h, b0[kk].h, acc0, 0, 0, 0);

    U4H8 b1f[7];
    if (TWO) {
        #pragma unroll
        for (int kk = 0; kk < 7; kk++)
            b1f[kk].u = WBl[((t0 + 16) * 7 + kk) * 64 + lane];
    }

    {   // tile t0 update (overlaps b1f L2 latency)
        float h = cell_update(acc0, g, cst[0]);
        int row = 4 * q + g;
        int uu  = 4 * t0 + v;
        dstA[row * PITCH + offA + uu] = (_Float16)h;
        if (dstB) dstB[row * PITCH + offB + uu] = (_Float16)h;
    }
    if (TWO) {
        v4f acc1 = { bl[1], bl[1], bl[1], bl[1] };
        #pragma unroll
        for (int kk = 0; kk < 7; kk++)
            acc1 = __builtin_amdgcn_mfma_f32_16x16x32_f16(af[kk].h, b1f[kk].h, acc1, 0, 0, 0);
        float h = cell_update(acc1, g, cst[1]);
        int row = 4 * q + g;
        int uu  = 4 * (t0 + 16) + v;
        dstA[row * PITCH + offA + uu] = (_Float16)h;
        if (dstB) dstB[row * PITCH + offB + uu] = (_Float16)h;
    }
}

__global__ __launch_bounds__(NTHR, 4) void lstm_main(
    const int*   __restrict__ features,   // [B][T]
    const float* __restrict__ embedding,  // [VOCAB][100]
    const float* __restrict__ b1,         // [400] gate-major
    const float* __restrict__ b2,
    const float* __restrict__ w_fc1,      // [100][128]
    const float* __restrict__ b_fc1,      // [128]
    const float* __restrict__ w_fc2,      // [128][2]
    const float* __restrict__ b_fc2,      // [2]
    const uint4* __restrict__ WB,         // [2][25][7][64] frags
    float*       __restrict__ out)        // [B][2]
{
    __shared__ alignas(16) _Float16 xh1[2][ROWS][PITCH];  // [x | h1 | pad]
    __shared__ alignas(16) _Float16 xh2[2][ROWS][PITCH];  // [h1 | h2 | pad]

    const int tid  = threadIdx.x;
    const int lane = tid & 63;
    const int wv   = tid >> 6;            // 0..15
    const int n    = lane & 15;
    const int g    = n & 3, v = n >> 2;
    const int blk  = blockIdx.x;
    const bool two = (wv < 9);            // tiles {wv, wv+16} else {wv}

    const uint4* WB1 = WB;
    const uint4* WB2 = WB + 25 * 7 * 64;

    // per-tile biases for this lane's column: tile t -> col c = g*100+(4t+v)
    float bl1[2] = {0, 0}, bl2[2] = {0, 0};
    {
        int cc0 = g * 100 + (4 * wv + v);
        bl1[0] = b1[cc0];
        bl2[0] = b2[cc0];
        if (two) {
            int cc1 = g * 100 + (4 * (wv + 16) + v);
            bl1[1] = b1[cc1];
            bl2[1] = b2[cc1];
        }
    }
    float c1[2] = {0, 0}, c2[2] = {0, 0};

    // zero all xh buffers (incl. the k>=200 pad that MFMA A-frags touch)
    {
        unsigned* p1 = (unsigned*)&xh1[0][0][0];
        unsigned* p2 = (unsigned*)&xh2[0][0][0];
        const int ndw = 2 * ROWS * PITCH / 2;     // dwords per array
        for (int i = tid; i < ndw; i += NTHR) { p1[i] = 0u; p2[i] = 0u; }
    }
    // stage x(0)
    const int rowx = tid / 25, px = tid % 25;     // tid<400: (row, 16B chunk)
    if (tid < 400) {
        int f0 = features[(blk * ROWS + rowx) * Tn + 0];
        float4 e = *(const float4*)(embedding + (size_t)f0 * Hn + 4 * px);
        union { _Float16 h[4]; uint2 u; } pk;
        pk.h[0] = (_Float16)e.x; pk.h[1] = (_Float16)e.y;
        pk.h[2] = (_Float16)e.z; pk.h[3] = (_Float16)e.w;
        *(uint2*)&xh1[0][rowx][4 * px] = pk.u;
    }
    __syncthreads();

    for (int t = 0; t < Tn; t++) {
        const int cur = t & 1, nxt = cur ^ 1;

        // prefetch x(t+1) (consumed at end of step; latency hidden)
        float4 xp = {0, 0, 0, 0};
        const bool hasx = (tid < 400) && (t + 1 < Tn);
        if (hasx) {
            int f = features[(blk * ROWS + rowx) * Tn + t + 1];
            xp = *(const float4*)(embedding + (size_t)f * Hn + 4 * px);
        }

        // Layer 1: reads xh1[cur]; h1 -> xh1[nxt][100+] and xh2[cur][0+]
        if (two)
            layer_phase<true >(WB1, wv, &xh1[cur][0][0], &xh1[nxt][0][0], 100,
                               &xh2[cur][0][0], 0, bl1, c1, lane);
        else
            layer_phase<false>(WB1, wv, &xh1[cur][0][0], &xh1[nxt][0][0], 100,
                               &xh2[cur][0][0], 0, bl1, c1, lane);
        __syncthreads();   // h1 visible before layer-2 reads xh2[cur]

        // Layer 2: reads xh2[cur]; h2 -> xh2[nxt][100+]
        if (two)
            layer_phase<true >(WB2, wv, &xh2[cur][0][0], &xh2[nxt][0][0], 100,
                               (_Float16*)nullptr, 0, bl2, c2, lane);
        else
            layer_phase<false>(WB2, wv, &xh2[cur][0][0], &xh2[nxt][0][0], 100,
                               (_Float16*)nullptr, 0, bl2, c2, lane);

        // publish x(t+1) into xh1[nxt][0..100)
        if (hasx) {
            union { _Float16 h[4]; uint2 u; } pk;
            pk.h[0] = (_Float16)xp.x; pk.h[1] = (_Float16)xp.y;
            pk.h[2] = (_Float16)xp.z; pk.h[3] = (_Float16)xp.w;
            *(uint2*)&xh1[nxt][rowx][4 * px] = pk.u;
        }
        __syncthreads();   // h2/x visible before next step
    }

    // FC head: final h2 in xh2[Tn&1][row][100..200); wave wv -> row wv.
    {
        const _Float16* hp = &xh2[Tn & 1][wv][100];
        float acc0 = b_fc1[lane];
        float acc1 = b_fc1[lane + 64];
        for (int u = 0; u < Hn; u++) {
            float hv = (float)hp[u];                       // LDS broadcast
            acc0 = fmaf(hv, w_fc1[u * FCn + lane], acc0);
            acc1 = fmaf(hv, w_fc1[u * FCn + lane + 64], acc1);
        }
        float p0 = acc0 * w_fc2[2 * lane + 0] + acc1 * w_fc2[2 * (lane + 64) + 0];
        float p1 = acc0 * w_fc2[2 * lane + 1] + acc1 * w_fc2[2 * (lane + 64) + 1];
        #pragma unroll
        for (int off = 32; off > 0; off >>= 1) {
            p0 += __shfl_down(p0, off);
            p1 += __shfl_down(p1, off);
        }
        if (lane == 0) {
            out[(blk * ROWS + wv) * 2 + 0] = p0 + b_fc2[0];
            out[(blk * ROWS + wv) * 2 + 1] = p1 + b_fc2[1];
        }
    }
}

extern "C" void kernel_launch(void* const* d_in, const int* in_sizes, int n_in,
                              void* d_out, int out_size, void* d_ws, size_t ws_size,
                              hipStream_t stream) {
    const int*   features  = (const int*)  d_in[0];
    const float* embedding = (const float*)d_in[1];
    const float* k1        = (const float*)d_in[2];
    const float* b1        = (const float*)d_in[3];
    const float* k2        = (const float*)d_in[4];
    const float* b2        = (const float*)d_in[5];
    const float* w_fc1     = (const float*)d_in[6];
    const float* b_fc1     = (const float*)d_in[7];
    const float* w_fc2     = (const float*)d_in[8];
    const float* b_fc2     = (const float*)d_in[9];

    uint4* WBp = (uint4*)d_ws;    // 2*25*7*64*16 = 358,400 B

    prep_weights<<<(2 * 25 * 7 * 64 + 255) / 256, 256, 0, stream>>>(k1, k2, WBp);
    lstm_main<<<NBLK, NTHR, 0, stream>>>(features, embedding, b1, b2,
                                         w_fc1, b_fc1, w_fc2, b_fc2,
                                         WBp, (float*)d_out);
}